// Round 6
// baseline (112.659 us; speedup 1.0000x reference)
//
#include <hip/hip_runtime.h>

#define IMG_W 2048
#define NUM_NODES 255
#define NLEAF 128
#define DEPTH 7
#define RS 68                       // padded LDS row stride (floats); 16B-chunk group = (row+q)%8

// DPP xor-butterfly add over 16-lane groups (VALU pipe, not LDS).
// Masks {1,2,7,8}: after xor1,xor2 all quad lanes hold the quad sum; xor7 adds the
// other quad of the 8-group; xor8 the other 8-group. All 16 lanes end bit-identical.
template<int CTRL>
__device__ __forceinline__ float dpp_add(float x) {
    int v = __builtin_amdgcn_update_dpp(0, __float_as_int(x), CTRL, 0xF, 0xF, true);
    return x + __int_as_float(v);
}
__device__ __forceinline__ float group16_sum(float x) {
    x = dpp_add<0xB1>(x);   // quad_perm [1,0,3,2]  : xor 1
    x = dpp_add<0x4E>(x);   // quad_perm [2,3,0,1]  : xor 2
    x = dpp_add<0x141>(x);  // row_half_mirror      : xor 7
    x = dpp_add<0x128>(x);  // row_ror:8            : xor 8
    return x;
}

// ---------------- K1: fused descend + per-leaf accumulate, 16 lanes/patch ----
// LDS = node table only (69.4 KB) -> 2 blocks/CU, 32 waves/CU. Sl overlays the
// node table after descent (leaves held in registers across the phase switch).
__global__ __launch_bounds__(1024, 8) void fusedK(const float* __restrict__ img,
                                                  const float* __restrict__ nodes,
                                                  float* __restrict__ leaf_out,
                                                  float* __restrict__ S,
                                                  unsigned* __restrict__ cnt)
{
    __shared__ float nds[NUM_NODES * RS];   // 69360 B; first 128*RS floats reused as Sl
    __shared__ unsigned cntl[NLEAF];
    float* Sl = nds;                        // overlay (phase 2)

    const int t = threadIdx.x;
    const int b = blockIdx.x;
    const int g = t >> 4;          // patch-group 0..63
    const int q = t & 15;          // quad within patch (elements 4q..4q+3)
    const int q4 = q * 4;

    if (t < NLEAF) cntl[t] = 0u;

    // fill node table (padded rows)
    const float4* ng = (const float4*)nodes;
    for (int i = t; i < NUM_NODES * 16; i += 1024) {
        *(float4*)&nds[(i >> 4) * RS + (i & 15) * 4] = ng[i];
    }

    // prefetch both chunks' patch quads (element e=4q+j -> pixel (q>>1, (q&1)*4+j))
    float4 xv[2];
    int pid[2];
    #pragma unroll
    for (int ch = 0; ch < 2; ++ch) {
        const int p = b * 128 + ch * 64 + g;
        pid[ch] = p;
        const int r = p >> 8, c = p & 255;
        xv[ch] = *(const float4*)(img + (size_t)(r * 8 + (q >> 1)) * IMG_W + c * 8 + (q & 1) * 4);
    }
    __syncthreads();

    // phase 1: descent (nodes from LDS; group-balanced banks regardless of row data)
    int leaf[2];
    #pragma unroll
    for (int ch = 0; ch < 2; ++ch) {
        const float4 x = xv[ch];
        int cur = 0;
        #pragma unroll
        for (int lvl = 0; lvl < DEPTH; ++lvl) {
            const int c0 = 2 * cur + 1;
            const float* base = &nds[c0 * RS + q4];
            const float4 a  = *(const float4*)(base);        // child c0, quad q
            const float4 bb = *(const float4*)(base + RS);   // child c0+1, quad q
            float s0 = 0.f, s1 = 0.f, d;
            d = a.x  - x.x; s0 = fmaf(d, d, s0);
            d = a.y  - x.y; s0 = fmaf(d, d, s0);
            d = a.z  - x.z; s0 = fmaf(d, d, s0);
            d = a.w  - x.w; s0 = fmaf(d, d, s0);
            d = bb.x - x.x; s1 = fmaf(d, d, s1);
            d = bb.y - x.y; s1 = fmaf(d, d, s1);
            d = bb.z - x.z; s1 = fmaf(d, d, s1);
            d = bb.w - x.w; s1 = fmaf(d, d, s1);
            s0 = group16_sum(s0);
            s1 = group16_sum(s1);
            cur = (s1 < s0) ? (c0 + 1) : c0;   // ref: d1 < d0 picks c1 (strict)
        }
        leaf[ch] = cur;
        if (q == 0) leaf_out[pid[ch]] = (float)cur;
    }
    __syncthreads();                        // all descents done reading nds

    // phase 2: overlay -> zero per-leaf accumulators
    for (int i = t; i < NLEAF * RS; i += 1024) Sl[i] = 0.0f;
    __syncthreads();

    #pragma unroll
    for (int ch = 0; ch < 2; ++ch) {
        const int L = leaf[ch] - 127;
        const float4 x = xv[ch];
        float* dst = &Sl[L * RS + q4];      // group (L+q)%8: balanced for random L
        atomicAdd(dst + 0, x.x);
        atomicAdd(dst + 1, x.y);
        atomicAdd(dst + 2, x.z);
        atomicAdd(dst + 3, x.w);
        if (q == 0) atomicAdd(&cntl[L], 1u);
    }
    __syncthreads();

    // flush block sums to global S (skip zeros; ~37% of rows untouched at 128 patches)
    for (int i = t; i < NLEAF * 64; i += 1024) {
        const float v = Sl[(i >> 6) * RS + (i & 63)];
        if (v != 0.0f) atomicAdd(&S[i], v);
    }
    if (t < NLEAF && cntl[t] != 0u) atomicAdd(&cnt[t], cntl[t]);
}

// ---------------- K2: node update (254x64x128 contraction) -------------------
__global__ __launch_bounds__(256) void updateK(const float* __restrict__ nodes,
                                               const float* __restrict__ S,
                                               const unsigned* __restrict__ cnt,
                                               float* __restrict__ out)
{
    const int gid = blockIdx.x * 256 + threadIdx.x;
    if (gid >= NUM_NODES * 64) return;
    const int n = gid >> 6, k = gid & 63;
    const float nd = nodes[gid];
    if (n == 0) { out[gid] = nd; return; }

    const int pos = n + 1;                 // 1-based heap index
    const int Ln = 31 - __clz(pos);        // node level, 1..7
    float su = 0.f, sc = 0.f;
    #pragma unroll 8
    for (int L = 0; L < NLEAF; ++L) {
        const int a = (128 + L) >> (7 - Ln);   // leaf's ancestor at level Ln
        const int x = pos ^ a;
        const int state = (x == 0) ? Ln : (Ln - (31 - __clz(x)) - 1);
        const float lr = 0.3f * ((float)(1 << state) * (1.0f / 128.0f));
        su = fmaf(lr, S[L * 64 + k], su);
        sc = fmaf(lr, (float)cnt[L], sc);
    }
    const float invP = 1.0f / 65536.0f;
    out[gid] = nd + su * invP - (sc * invP) * nd;
}

extern "C" void kernel_launch(void* const* d_in, const int* in_sizes, int n_in,
                              void* d_out, int out_size, void* d_ws, size_t ws_size,
                              hipStream_t stream)
{
    const float* img   = (const float*)d_in[0];   // 2048*2048 f32
    const float* nodes = (const float*)d_in[1];   // 255*64 f32

    float* out_nodes = (float*)d_out;                 // 255*64
    float* out_leaf  = out_nodes + NUM_NODES * 64;    // 65536 (leaf index as f32)

    float*    S   = (float*)d_ws;                     // 128*64 f32
    unsigned* cnt = (unsigned*)(S + NLEAF * 64);      // 128 u32

    hipMemsetAsync(d_ws, 0, (NLEAF * 64) * sizeof(float) + NLEAF * sizeof(unsigned), stream);
    fusedK<<<512, 1024, 0, stream>>>(img, nodes, out_leaf, S, cnt);
    updateK<<<64, 256, 0, stream>>>(nodes, S, cnt, out_nodes);
}